// Round 1
// baseline (348.366 us; speedup 1.0000x reference)
//
#include <hip/hip_runtime.h>
#include <hip/hip_bf16.h>

#define NT 256

namespace {

constexpr int kL0 = 8192;
constexpr int kL1 = 4100;  // (8192+6)/2 + 1
constexpr int kL2 = 2054;  // (4100+6)/2 + 1
constexpr int kL3 = 1031;  // (2054+6)/2 + 1
constexpr int kRows = 16 * 128;  // 2048

// Analysis: out[i] = sum_k w[k] * xp[2i+k], xp = reflect-pad(K-1=7) of src.
// Computes both lo and hi bands in one pass (shares the 8 loads).
__device__ __forceinline__ void analysis8(const float* __restrict__ s, int L, int Lo,
                                          float* __restrict__ alo, float* __restrict__ ahi)
{
  constexpr float lo[8] = {-0.0105974018f, 0.0328830117f, 0.0308413818f, -0.1870348117f,
                           -0.0279837694f, 0.6308807679f, 0.7148465706f, 0.2303778133f};
  constexpr float hi[8] = {-0.2303778133f, 0.7148465706f, -0.6308807679f, -0.0279837694f,
                           0.1870348117f, 0.0308413818f, -0.0328830117f, -0.0105974018f};
  for (int i = (int)threadIdx.x; i < Lo; i += NT) {
    const int base = 2 * i - 7;
    float slo = 0.f, shi = 0.f;
#pragma unroll
    for (int k = 0; k < 8; ++k) {
      int m = base + k;
      m = (m < 0) ? -m : m;               // single reflection suffices (overhang <= 7)
      m = (m >= L) ? (2 * L - 2 - m) : m;
      const float v = s[m];
      slo = fmaf(lo[k], v, slo);
      shi = fmaf(hi[k], v, shi);
    }
    alo[i] = slo;
    ahi[i] = shi;
  }
}

// Transposed conv (stride 2) + center-crop(7) fused: 4-tap polyphase, no bounds checks.
// even i: taps (w7,w5,w3,w1); odd i: taps (w6,w4,w2,w0); src index q=(i+1)>>1.
__device__ __forceinline__ void synthT(const float* __restrict__ s, float* __restrict__ d, int T,
                                       float e0, float e1, float e2, float e3,
                                       float o0, float o1, float o2, float o3)
{
  for (int i = (int)threadIdx.x; i < T; i += NT) {
    const int q = (i + 1) >> 1;
    const bool odd = (i & 1) != 0;
    const float c0 = odd ? o0 : e0;
    const float c1 = odd ? o1 : e1;
    const float c2 = odd ? o2 : e2;
    const float c3 = odd ? o3 : e3;
    float r = c0 * s[q];
    r = fmaf(c1, s[q + 1], r);
    r = fmaf(c2, s[q + 2], r);
    r = fmaf(c3, s[q + 3], r);
    d[i] = r;
  }
}

// REC_LO = {0.2303778133, 0.7148465706, 0.6308807679, -0.0279837694,
//           -0.1870348117, 0.0308413818, 0.0328830117, -0.0105974018}
#define RL_E -0.0105974018f, 0.0308413818f, -0.0279837694f, 0.7148465706f
#define RL_O 0.0328830117f, -0.1870348117f, 0.6308807679f, 0.2303778133f
// REC_HI = {-0.0105974018, -0.0328830117, 0.0308413818, 0.1870348117,
//           -0.0279837694, -0.6308807679, 0.7148465706, -0.2303778133}
#define RH_E -0.2303778133f, -0.6308807679f, 0.1870348117f, -0.0328830117f
#define RH_O 0.7148465706f, -0.0279837694f, 0.0308413818f, -0.0105974018f

// LDS pool (floats), carefully aliased. Peak live ~8216 floats.
//   a1   [0,4104)        live: steps 1-3
//   d1   [4104,8208)     live: steps 1-2
//   a2   [4104,6160)     live: steps 3-6
//   d2   [6160,8216)     live: steps 3-4
//   t2b2 [0,4104)        live: steps 4-5 (a1 dead)
//   a3   [0,1032)        live: steps 6-10
//   d3   [1032,2064)     live: steps 6-7
//   t1   [2064,4120)     live: 7-8 / 10-11
//   t2   [4120,8224)     live: 8-9 / 11-12
constexpr int kPool = 8224;

__global__ __launch_bounds__(NT, 4) void dwt_front(const float* __restrict__ x,
                                                   float* __restrict__ out)
{
  __shared__ float pool[kPool];
  const int row = blockIdx.x;
  const float* __restrict__ xr = x + (size_t)row * kL0;
  float* __restrict__ outr = out + (size_t)row * kL0;
  const size_t bs = (size_t)kRows * kL0;  // band stride

  float* a1   = pool + 0;
  float* d1   = pool + 4104;
  float* a2   = pool + 4104;
  float* d2   = pool + 6160;
  float* t2b2 = pool + 0;
  float* a3   = pool + 0;
  float* d3   = pool + 1032;
  float* t1   = pool + 2064;
  float* t2   = pool + 4120;

  // 1. level-1 analysis from global x
  analysis8(xr, kL0, kL1, a1, d1);
  __syncthreads();
  // 2. band 3 = fit(convT(d1, REC_HI), 8192) -> global
  synthT(d1, outr + 3 * bs, kL0, RH_E, RH_O);
  __syncthreads();
  // 3. level-2 analysis (d1 dead -> a2/d2 overwrite its slot)
  analysis8(a1, kL1, kL2, a2, d2);
  __syncthreads();
  // 4. band 2 stage 1: t2b2 = fit(convT(d2, REC_HI), 4100)   (a1 dead)
  synthT(d2, t2b2, kL1, RH_E, RH_O);
  __syncthreads();
  // 5. band 2 stage 2 -> global
  synthT(t2b2, outr + 2 * bs, kL0, RL_E, RL_O);
  __syncthreads();
  // 6. level-3 analysis (t2b2 dead)
  analysis8(a2, kL2, kL3, a3, d3);
  __syncthreads();
  // 7-9. band 1: d3 -> t1 -> t2 -> global
  synthT(d3, t1, kL2, RH_E, RH_O);
  __syncthreads();
  synthT(t1, t2, kL1, RL_E, RL_O);
  __syncthreads();
  synthT(t2, outr + 1 * bs, kL0, RL_E, RL_O);
  __syncthreads();
  // 10-12. band 0: a3 -> t1 -> t2 -> global
  synthT(a3, t1, kL2, RL_E, RL_O);
  __syncthreads();
  synthT(t1, t2, kL1, RL_E, RL_O);
  __syncthreads();
  synthT(t2, outr + 0 * bs, kL0, RL_E, RL_O);
}

}  // namespace

extern "C" void kernel_launch(void* const* d_in, const int* in_sizes, int n_in,
                              void* d_out, int out_size, void* d_ws, size_t ws_size,
                              hipStream_t stream)
{
  const float* x = (const float*)d_in[0];
  float* out = (float*)d_out;
  dwt_front<<<dim3(kRows), dim3(NT), 0, stream>>>(x, out);
}

// Round 2
// 310.471 us; speedup vs baseline: 1.1221x; 1.1221x over previous
//
#include <hip/hip_runtime.h>
#include <hip/hip_bf16.h>

#define NT 256

namespace {

constexpr int kL0 = 8192;
constexpr int kL1 = 4100;  // (8192+6)/2 + 1
constexpr int kL2 = 2054;  // (4100+6)/2 + 1
constexpr int kL3 = 1031;  // (2054+6)/2 + 1
constexpr int kRows = 16 * 128;  // 2048

__constant__ __device__ const float kLO[8] = {-0.0105974018f, 0.0328830117f, 0.0308413818f, -0.1870348117f,
                                              -0.0279837694f, 0.6308807679f, 0.7148465706f, 0.2303778133f};
__constant__ __device__ const float kHI[8] = {-0.2303778133f, 0.7148465706f, -0.6308807679f, -0.0279837694f,
                                              0.1870348117f, 0.0308413818f, -0.0328830117f, -0.0105974018f};

// ---- Analysis: out[i] = sum_k w[k] * xp[2i+k], xp = reflect-pad(7).
// Pair-processing: outputs (2u, 2u+1) read s[4u-7 .. 4u+2]; interior pairs
// load s[4u-8 .. 4u+3] as 3 aligned float4 (global dwordx4 / ds_read_b128).
__device__ __forceinline__ void analysis2(const float* __restrict__ s, int L, int Lo,
                                          float* __restrict__ alo, float* __restrict__ ahi)
{
  const int npairs = Lo >> 1;
  const int uHi = (L - 3) >> 2;  // last interior pair: 4u+2 <= L-1
  for (int u = (int)threadIdx.x; u < npairs; u += NT) {
    if (u >= 2 && u <= uHi) {
      const float4* s4 = (const float4*)(s + 4 * u - 8);
      const float4 v0 = s4[0], v1 = s4[1], v2 = s4[2];
      const float w[10] = {v0.y, v0.z, v0.w, v1.x, v1.y, v1.z, v1.w, v2.x, v2.y, v2.z};
      float lo0 = 0.f, hi0 = 0.f, lo1 = 0.f, hi1 = 0.f;
#pragma unroll
      for (int k = 0; k < 8; ++k) {
        lo0 = fmaf(kLO[k], w[k], lo0);
        hi0 = fmaf(kHI[k], w[k], hi0);
        lo1 = fmaf(kLO[k], w[k + 2], lo1);
        hi1 = fmaf(kHI[k], w[k + 2], hi1);
      }
      ((float2*)alo)[u] = make_float2(lo0, lo1);
      ((float2*)ahi)[u] = make_float2(hi0, hi1);
    } else {
      // boundary: scalar reflect path for outputs 2u and 2u+1
#pragma unroll
      for (int j = 0; j < 2; ++j) {
        const int i = 2 * u + j;
        const int base = 2 * i - 7;
        float slo = 0.f, shi = 0.f;
#pragma unroll
        for (int k = 0; k < 8; ++k) {
          int m = base + k;
          m = (m < 0) ? -m : m;
          m = (m >= L) ? (2 * L - 2 - m) : m;
          const float v = s[m];
          slo = fmaf(kLO[k], v, slo);
          shi = fmaf(kHI[k], v, shi);
        }
        alo[i] = slo;
        ahi[i] = shi;
      }
    }
  }
  if ((Lo & 1) && threadIdx.x == 0) {  // odd tail (level 3: Lo=1031)
    const int i = Lo - 1;
    const int base = 2 * i - 7;
    float slo = 0.f, shi = 0.f;
#pragma unroll
    for (int k = 0; k < 8; ++k) {
      int m = base + k;
      m = (m < 0) ? -m : m;
      m = (m >= L) ? (2 * L - 2 - m) : m;
      const float v = s[m];
      slo = fmaf(kLO[k], v, slo);
      shi = fmaf(kHI[k], v, shi);
    }
    alo[i] = slo;
    ahi[i] = shi;
  }
}

// ---- Transposed conv (stride 2) + center-crop(7), 4-tap polyphase.
// even i: taps (w7,w5,w3,w1) over s[q..q+3], q=(i+1)>>1; odd i: (w6,w4,w2,w0).
// Quad-processing: outputs 4t..4t+3 read s[2t..2t+5] = 3 float2; store float4.
__device__ __forceinline__ void synthT4(const float* __restrict__ s, float* __restrict__ d, int T,
                                        float e0, float e1, float e2, float e3,
                                        float o0, float o1, float o2, float o3)
{
  const float2* __restrict__ s2 = (const float2*)s;
  const int nq = T >> 2;
  for (int t = (int)threadIdx.x; t < nq; t += NT) {
    const float2 p0 = s2[t];          // s[2t],   s[2t+1]
    const float2 p1 = s2[t + 1];      // s[2t+2], s[2t+3]
    const float2 p2 = s2[t + 2];      // s[2t+4], s[2t+5]
    float4 r;
    r.x = fmaf(e3, p1.y, fmaf(e2, p1.x, fmaf(e1, p0.y, e0 * p0.x)));
    r.y = fmaf(o3, p2.x, fmaf(o2, p1.y, fmaf(o1, p1.x, o0 * p0.y)));
    r.z = fmaf(e3, p2.x, fmaf(e2, p1.y, fmaf(e1, p1.x, e0 * p0.y)));
    r.w = fmaf(o3, p2.y, fmaf(o2, p2.x, fmaf(o1, p1.y, o0 * p1.x)));
    ((float4*)d)[t] = r;
  }
  // tail (T % 4 == 2 for T=2054)
  const int i0 = T & ~3;
  for (int i = i0 + (int)threadIdx.x; i < T; i += NT) {
    const int q = (i + 1) >> 1;
    const bool odd = (i & 1) != 0;
    const float c0 = odd ? o0 : e0;
    const float c1 = odd ? o1 : e1;
    const float c2 = odd ? o2 : e2;
    const float c3 = odd ? o3 : e3;
    float r = c0 * s[q];
    r = fmaf(c1, s[q + 1], r);
    r = fmaf(c2, s[q + 2], r);
    r = fmaf(c3, s[q + 3], r);
    d[i] = r;
  }
}

// REC_LO polyphase taps
#define RL_E -0.0105974018f, 0.0308413818f, -0.0279837694f, 0.7148465706f
#define RL_O 0.0328830117f, -0.1870348117f, 0.6308807679f, 0.2303778133f
// REC_HI polyphase taps
#define RH_E -0.2303778133f, -0.6308807679f, 0.1870348117f, -0.0328830117f
#define RH_O 0.7148465706f, -0.0279837694f, 0.0308413818f, -0.0105974018f

// LDS pool (floats), aliased; all slot bases are multiples of 4 floats (16 B).
constexpr int kPool = 8224;

__global__ __launch_bounds__(NT, 4) void dwt_front(const float* __restrict__ x,
                                                   float* __restrict__ out)
{
  __shared__ float pool[kPool];
  const int row = blockIdx.x;
  const float* __restrict__ xr = x + (size_t)row * kL0;
  float* __restrict__ outr = out + (size_t)row * kL0;
  const size_t bs = (size_t)kRows * kL0;  // band stride

  float* a1   = pool + 0;     // [0,4104)    steps 1-3
  float* d1   = pool + 4104;  // [4104,8208) steps 1-2
  float* a2   = pool + 4104;  // [4104,6160) steps 3-6
  float* d2   = pool + 6160;  // [6160,8216) steps 3-4
  float* t2b2 = pool + 0;     // [0,4104)    steps 4-5 (a1 dead)
  float* a3   = pool + 0;     // [0,1032)    steps 6-10
  float* d3   = pool + 1032;  // [1032,2064) steps 6-7
  float* t1   = pool + 2064;  // [2064,4120)
  float* t2   = pool + 4120;  // [4120,8224)

  // 1. level-1 analysis from global x
  analysis2(xr, kL0, kL1, a1, d1);
  __syncthreads();
  // 2. band 3 = fit(convT(d1, REC_HI), 8192) -> global
  synthT4(d1, outr + 3 * bs, kL0, RH_E, RH_O);
  __syncthreads();
  // 3. level-2 analysis (d1 dead)
  analysis2(a1, kL1, kL2, a2, d2);
  __syncthreads();
  // 4. band 2 stage 1 (a1 dead)
  synthT4(d2, t2b2, kL1, RH_E, RH_O);
  __syncthreads();
  // 5. band 2 stage 2 -> global
  synthT4(t2b2, outr + 2 * bs, kL0, RL_E, RL_O);
  __syncthreads();
  // 6. level-3 analysis (t2b2 dead)
  analysis2(a2, kL2, kL3, a3, d3);
  __syncthreads();
  // 7-9. band 1: d3 -> t1 -> t2 -> global
  synthT4(d3, t1, kL2, RH_E, RH_O);
  __syncthreads();
  synthT4(t1, t2, kL1, RL_E, RL_O);
  __syncthreads();
  synthT4(t2, outr + 1 * bs, kL0, RL_E, RL_O);
  __syncthreads();
  // 10-12. band 0: a3 -> t1 -> t2 -> global
  synthT4(a3, t1, kL2, RL_E, RL_O);
  __syncthreads();
  synthT4(t1, t2, kL1, RL_E, RL_O);
  __syncthreads();
  synthT4(t2, outr + 0 * bs, kL0, RL_E, RL_O);
}

}  // namespace

extern "C" void kernel_launch(void* const* d_in, const int* in_sizes, int n_in,
                              void* d_out, int out_size, void* d_ws, size_t ws_size,
                              hipStream_t stream)
{
  const float* x = (const float*)d_in[0];
  float* out = (float*)d_out;
  dwt_front<<<dim3(kRows), dim3(NT), 0, stream>>>(x, out);
}